// Round 1
// baseline (929.389 us; speedup 1.0000x reference)
//
#include <hip/hip_runtime.h>
#include <hip/hip_bf16.h>

// ScaledDotProductAttention: B=2,H=16,S=2048,D=64, fp32 in/out.
// d_out = output[2,16,2048,64] ++ score[2,16,2048,2048] (flat fp32).
//
// R3: latency-bound fix (all pipes were idle: Mfma 4.9%, VALU 22%, occ 38%).
//  (a) Swapped-operand QK^T: mfma(K,Q) -> lane holds scores of its own q-row.
//      Mask load 4->1 dword/iter, score stores 8 scalar -> 2 float4,
//      P->A-frag transpose = 4 VALU permlane swaps (no LDS, no barriers).
//  (b) Column-split: each wave does 16 rows x 1024 cols; wave pairs combine
//      l and O via small LDS. Grid 2048 blocks -> 8 waves/SIMD (2x occupancy).
// Two-pass softmax without max-subtraction (scores bounded ~+/-6; exp can't
// overflow fp32; matches jax.nn.softmax in exact arithmetic).

#define BH 32
#define SEQ 2048
#define DIM 64

typedef __attribute__((ext_vector_type(8))) short short8;
typedef __attribute__((ext_vector_type(4))) float floatx4;
typedef __attribute__((ext_vector_type(4))) unsigned int uintx4;

__device__ __forceinline__ short f2bf(float f) {
    unsigned u = __builtin_bit_cast(unsigned, f);
    unsigned r = u + 0x7fffu + ((u >> 16) & 1u);   // RNE; inputs finite
    return (short)(r >> 16);
}

// pack two fp32 -> one dword of 2 bf16 (lo in bits 15:0), RNE
__device__ __forceinline__ unsigned pack2bf(float lo, float hi) {
    unsigned ul = __builtin_bit_cast(unsigned, lo);
    unsigned uh = __builtin_bit_cast(unsigned, hi);
    ul = ul + 0x7fffu + ((ul >> 16) & 1u);
    uh = uh + 0x7fffu + ((uh >> 16) & 1u);
    return (ul >> 16) | (uh & 0xffff0000u);
}

__device__ __forceinline__ short8 cvt_frag(float4 a, float4 b) {
    short8 r;
    r[0] = f2bf(a.x); r[1] = f2bf(a.y); r[2] = f2bf(a.z); r[3] = f2bf(a.w);
    r[4] = f2bf(b.x); r[5] = f2bf(b.y); r[6] = f2bf(b.z); r[7] = f2bf(b.w);
    return r;
}

__device__ __forceinline__ short8 load_frag_f32(const float* p) {
    float4 a = *reinterpret_cast<const float4*>(p);
    float4 b = *reinterpret_cast<const float4*>(p + 4);
    return cvt_frag(a, b);
}

// ---------------------------------------------------------------- prep kernels

__global__ void maskbits_kernel(const int* __restrict__ mask,
                                unsigned long long* __restrict__ bits) {
    int tid = blockIdx.x * blockDim.x + threadIdx.x;
    unsigned long long b = __ballot(mask[tid] != 0);
    if ((threadIdx.x & 63) == 0) bits[tid >> 6] = b;
}

// K fp32 row-major -> bf16 row-major (identical memory order).
__global__ void cvt_k_kernel(const float* __restrict__ k, short* __restrict__ kb) {
    size_t i = ((size_t)blockIdx.x * blockDim.x + threadIdx.x) * 8;
    float4 a = *reinterpret_cast<const float4*>(k + i);
    float4 b = *reinterpret_cast<const float4*>(k + i + 4);
    *reinterpret_cast<short8*>(kb + i) = cvt_frag(a, b);
}

// V fp32 [bh][s][d] -> bf16 transposed [bh][d][s], via LDS 64x64 tile.
__global__ __launch_bounds__(256) void cvt_vt_kernel(const float* __restrict__ v,
                                                     short* __restrict__ vt) {
    __shared__ float tile[64][65];
    const int bh = blockIdx.y;
    const int sblk = blockIdx.x;          // 32 blocks of 64 s-rows
    const int t = threadIdx.x;
    const float* vb = v + ((size_t)bh * SEQ + sblk * 64) * DIM;
#pragma unroll
    for (int it = 0; it < 4; ++it) {
        int row = it * 16 + (t >> 4);
        int c4 = (t & 15) * 4;
        float4 a = *reinterpret_cast<const float4*>(vb + row * DIM + c4);
        tile[row][c4] = a.x; tile[row][c4 + 1] = a.y;
        tile[row][c4 + 2] = a.z; tile[row][c4 + 3] = a.w;
    }
    __syncthreads();
    short* vo = vt + (size_t)bh * SEQ * DIM;
#pragma unroll
    for (int it = 0; it < 2; ++it) {
        int c = it * 256 + t;             // 512 chunks: d = c/8, s-offset = (c%8)*8
        int d = c >> 3;
        int s8 = (c & 7) * 8;
        short8 r;
#pragma unroll
        for (int j = 0; j < 8; ++j) r[j] = f2bf(tile[s8 + j][d]);
        *reinterpret_cast<short8*>(vo + (size_t)d * SEQ + sblk * 64 + s8) = r;
    }
}

// ---------------------------------------------------------------- fast attention

__global__ __launch_bounds__(256, 8) void attn_fast(
    const float* __restrict__ q, const short* __restrict__ kb,
    const short* __restrict__ vt, const unsigned int* __restrict__ maskbits,
    float* __restrict__ out, float* __restrict__ score)
{
    __shared__ float lpart[4][16];
    __shared__ float ocomb[2][4][4][64];

    const int bh   = blockIdx.y;
    const int qb   = blockIdx.x;              // 64 blocks of 32 q-rows
    const int wave = threadIdx.x >> 6;
    const int lane = threadIdx.x & 63;
    const int quad = lane >> 4;
    const int n    = lane & 15;
    const int half = wave & 1;                // column half this wave owns
    const int q0   = qb * 32 + (wave >> 1) * 16;
    const int q4   = quad * 4;
    const int cp0  = half * (SEQ / 64);       // 32 col-words per half
    const int cp1  = cp0 + (SEQ / 64);

    const float* qbase = q  + (size_t)bh * SEQ * DIM;
    const short* kbb   = kb + (size_t)bh * SEQ * DIM;
    const short* vtb   = vt + (size_t)bh * SEQ * DIM;

    // Q fragments (B-layout after swap: B[n=lane&15][k=quad*8+j]).
    const short8 qf0 = load_frag_f32(qbase + (size_t)(q0 + n) * DIM + quad * 8);
    const short8 qf1 = load_frag_f32(qbase + (size_t)(q0 + n) * DIM + 32 + quad * 8);

    // Hoisted per-lane bases.
    const short* kn  = kbb + (size_t)n * DIM + quad * 8;   // K row cbase+n
    const short* vn0 = vtb + (size_t)n * SEQ + quad * 8;   // V^T row d=n+16t
    const unsigned int* mr = maskbits + (size_t)(q0 + n) * (SEQ / 32);
    float* sb = score + (size_t)bh * SEQ * SEQ + (size_t)(q0 + n) * SEQ + q4;

    // ---------------- pass 1: l[row n] = sum exp(masked s) ----------------
    // Swapped mfma(K,Q): lane (quad,n) gets S[kcol = cbase+4*quad+r][qrow = n].
    float lsum = 0.f;
    for (int cp = cp0; cp < cp1; ++cp) {
        const int cbase = cp * 32;
        const short* k0 = kn + (size_t)cbase * DIM;
        short8 kf00 = *reinterpret_cast<const short8*>(k0);
        short8 kf01 = *reinterpret_cast<const short8*>(k0 + 32);
        short8 kf10 = *reinterpret_cast<const short8*>(k0 + 16 * DIM);
        short8 kf11 = *reinterpret_cast<const short8*>(k0 + 16 * DIM + 32);
        floatx4 a0 = {0.f, 0.f, 0.f, 0.f}, a1 = {0.f, 0.f, 0.f, 0.f};
        a0 = __builtin_amdgcn_mfma_f32_16x16x32_bf16(kf00, qf0, a0, 0, 0, 0);
        a0 = __builtin_amdgcn_mfma_f32_16x16x32_bf16(kf01, qf1, a0, 0, 0, 0);
        a1 = __builtin_amdgcn_mfma_f32_16x16x32_bf16(kf10, qf0, a1, 0, 0, 0);
        a1 = __builtin_amdgcn_mfma_f32_16x16x32_bf16(kf11, qf1, a1, 0, 0, 0);
        const unsigned w = mr[cp];
#pragma unroll
        for (int r = 0; r < 4; ++r) {
            float e0 = ((w >> (q4 + r)) & 1u)      ? __expf(a0[r] * 0.125f) : 0.f;
            float e1 = ((w >> (q4 + r + 16)) & 1u) ? __expf(a1[r] * 0.125f) : 0.f;
            lsum += e0 + e1;
        }
    }
    // reduce across quads (same n), then across the wave pair via LDS
    lsum += __shfl_xor(lsum, 16, 64);
    lsum += __shfl_xor(lsum, 32, 64);
    if (lane < 16) lpart[wave][lane] = lsum;
    __syncthreads();
    const float invl = 1.0f / (lsum + lpart[wave ^ 1][n]);

    // ---------------- pass 2: p -> score + PV ----------------
    floatx4 o[4];
#pragma unroll
    for (int t = 0; t < 4; ++t) o[t] = (floatx4){0.f, 0.f, 0.f, 0.f};

    for (int cp = cp0; cp < cp1; ++cp) {
        const int cbase = cp * 32;
        const short* k0 = kn + (size_t)cbase * DIM;
        short8 kf00 = *reinterpret_cast<const short8*>(k0);
        short8 kf01 = *reinterpret_cast<const short8*>(k0 + 32);
        short8 kf10 = *reinterpret_cast<const short8*>(k0 + 16 * DIM);
        short8 kf11 = *reinterpret_cast<const short8*>(k0 + 16 * DIM + 32);
        floatx4 a0 = {0.f, 0.f, 0.f, 0.f}, a1 = {0.f, 0.f, 0.f, 0.f};
        a0 = __builtin_amdgcn_mfma_f32_16x16x32_bf16(kf00, qf0, a0, 0, 0, 0);
        a0 = __builtin_amdgcn_mfma_f32_16x16x32_bf16(kf01, qf1, a0, 0, 0, 0);
        a1 = __builtin_amdgcn_mfma_f32_16x16x32_bf16(kf10, qf0, a1, 0, 0, 0);
        a1 = __builtin_amdgcn_mfma_f32_16x16x32_bf16(kf11, qf1, a1, 0, 0, 0);
        const unsigned w = mr[cp];
        float p0[4], p1[4];
#pragma unroll
        for (int r = 0; r < 4; ++r) {
            float e0 = ((w >> (q4 + r)) & 1u)      ? __expf(a0[r] * 0.125f) : 0.f;
            float e1 = ((w >> (q4 + r + 16)) & 1u) ? __expf(a1[r] * 0.125f) : 0.f;
            p0[r] = e0 * invl;
            p1[r] = e1 * invl;
        }
        // score: row n, cols cbase+4*quad+{0..3} and +16 — two float4 stores
        *reinterpret_cast<float4*>(sb + cbase)      = make_float4(p0[0], p0[1], p0[2], p0[3]);
        *reinterpret_cast<float4*>(sb + cbase + 16) = make_float4(p1[0], p1[1], p1[2], p1[3]);

        // P -> A-fragment (A[n][k=8*quad+j]) via pure-VALU permlane routing.
        // col-dword C(i)=cols(2i,2i+1): quad qd needs C(4qd..4qd+3).
        // swap32 then swap16 on (a0L,a1L) yields C(4q) and C(4q+2);
        // same on (a0H,a1H) yields C(4q+1) and C(4q+3).  (lane math verified)
        unsigned a0L = pack2bf(p0[0], p0[1]);
        unsigned a0H = pack2bf(p0[2], p0[3]);
        unsigned a1L = pack2bf(p1[0], p1[1]);
        unsigned a1H = pack2bf(p1[2], p1[3]);
        asm("v_permlane32_swap_b32 %0, %1" : "+v"(a0L), "+v"(a1L));
        asm("v_permlane16_swap_b32 %0, %1" : "+v"(a0L), "+v"(a1L));
        asm("v_permlane32_swap_b32 %0, %1" : "+v"(a0H), "+v"(a1H));
        asm("v_permlane16_swap_b32 %0, %1" : "+v"(a0H), "+v"(a1H));
        uintx4 pu = {a0L, a0H, a1L, a1H};      // dwords j: cols 8q+{0,1},{2,3},{4,5},{6,7}
        short8 pf = __builtin_bit_cast(short8, pu);

#pragma unroll
        for (int t = 0; t < 4; ++t) {
            short8 vf = *reinterpret_cast<const short8*>(vn0 + (size_t)t * 16 * SEQ + cbase);
            o[t] = __builtin_amdgcn_mfma_f32_16x16x32_bf16(pf, vf, o[t], 0, 0, 0);
        }
    }

    // ---------------- epilogue: combine O across the wave pair, write ----------------
    if (half) {
#pragma unroll
        for (int t = 0; t < 4; ++t)
#pragma unroll
            for (int r = 0; r < 4; ++r)
                ocomb[wave >> 1][t][r][lane] = o[t][r];
    }
    __syncthreads();
    if (!half) {
        float* obase = out + ((size_t)bh * SEQ + q0) * DIM;
#pragma unroll
        for (int t = 0; t < 4; ++t)
#pragma unroll
            for (int r = 0; r < 4; ++r)
                obase[(size_t)(quad * 4 + r) * DIM + t * 16 + n] =
                    o[t][r] + ocomb[wave >> 1][t][r][lane];
    }
}

// ---------------------------------------------------------------- fallback (R1)

__global__ __launch_bounds__(256) void attn_ref(
    const float* __restrict__ q, const float* __restrict__ k,
    const float* __restrict__ v, const int* __restrict__ mask,
    const unsigned int* __restrict__ maskbits, int use_bits,
    float* __restrict__ out, float* __restrict__ score)
{
    __shared__ float plds[4][16][36];
    const int bh   = blockIdx.y;
    const int qb   = blockIdx.x;
    const int wave = threadIdx.x >> 6;
    const int lane = threadIdx.x & 63;
    const int quad = lane >> 4;
    const int n    = lane & 15;
    const int q0   = qb * 64 + wave * 16;
    const float* qbase = q + (size_t)bh * SEQ * DIM;
    const float* kbase = k + (size_t)bh * SEQ * DIM;
    const float* vbase = v + (size_t)bh * SEQ * DIM;
    const short8 qf0 = load_frag_f32(qbase + (size_t)(q0 + n) * DIM + quad * 8);
    const short8 qf1 = load_frag_f32(qbase + (size_t)(q0 + n) * DIM + 32 + quad * 8);
    float l[4] = {0.f, 0.f, 0.f, 0.f};
    for (int ct = 0; ct < SEQ / 16; ++ct) {
        const int col0 = ct * 16;
        short8 kf0 = load_frag_f32(kbase + (size_t)(col0 + n) * DIM + quad * 8);
        short8 kf1 = load_frag_f32(kbase + (size_t)(col0 + n) * DIM + 32 + quad * 8);
        floatx4 acc = {0.f, 0.f, 0.f, 0.f};
        acc = __builtin_amdgcn_mfma_f32_16x16x32_bf16(qf0, kf0, acc, 0, 0, 0);
        acc = __builtin_amdgcn_mfma_f32_16x16x32_bf16(qf1, kf1, acc, 0, 0, 0);
#pragma unroll
        for (int r = 0; r < 4; ++r) {
            const int row = q0 + quad * 4 + r;
            int mbit;
            if (use_bits) {
                unsigned w = maskbits[((size_t)row * SEQ + col0) >> 5];
                mbit = (w >> ((col0 & 31) + n)) & 1;
            } else {
                mbit = (mask[(size_t)row * SEQ + col0 + n] != 0);
            }
            l[r] += mbit ? __expf(acc[r] * 0.125f) : 0.0f;
        }
    }
#pragma unroll
    for (int r = 0; r < 4; ++r) {
        float x = l[r];
        x += __shfl_xor(x, 1, 64);
        x += __shfl_xor(x, 2, 64);
        x += __shfl_xor(x, 4, 64);
        x += __shfl_xor(x, 8, 64);
        l[r] = 1.0f / x;
    }
    floatx4 o[4];
#pragma unroll
    for (int t = 0; t < 4; ++t) o[t] = (floatx4){0.f, 0.f, 0.f, 0.f};
    float* srow = score + (size_t)bh * SEQ * SEQ;
    for (int cp = 0; cp < SEQ / 32; ++cp) {
        const int cbase = cp * 32;
#pragma unroll
        for (int half = 0; half < 2; ++half) {
            const int col0 = cbase + half * 16;
            short8 kf0 = load_frag_f32(kbase + (size_t)(col0 + n) * DIM + quad * 8);
            short8 kf1 = load_frag_f32(kbase + (size_t)(col0 + n) * DIM + 32 + quad * 8);
            floatx4 acc = {0.f, 0.f, 0.f, 0.f};
            acc = __builtin_amdgcn_mfma_f32_16x16x32_bf16(qf0, kf0, acc, 0, 0, 0);
            acc = __builtin_amdgcn_mfma_f32_16x16x32_bf16(qf1, kf1, acc, 0, 0, 0);
#pragma unroll
            for (int r = 0; r < 4; ++r) {
                const int row = q0 + quad * 4 + r;
                int mbit;
                if (use_bits) {
                    unsigned w = maskbits[((size_t)row * SEQ + col0) >> 5];
                    mbit = (w >> ((col0 & 31) + n)) & 1;
                } else {
                    mbit = (mask[(size_t)row * SEQ + col0 + n] != 0);
                }
                float e = mbit ? __expf(acc[r] * 0.125f) : 0.0f;
                float p = e * l[r];
                srow[(size_t)row * SEQ + col0 + n] = p;
                plds[wave][quad * 4 + r][half * 16 + n] = p;
            }
        }
        short8 pf = load_frag_f32(&plds[wave][n][quad * 8]);
#pragma unroll
        for (int t = 0; t < 4; ++t) {
            short8 vf;
#pragma unroll
            for (int j = 0; j < 8; ++j)
                vf[j] = f2bf(vbase[(size_t)(cbase + quad * 8 + j) * DIM + t * 16 + n]);
            o[t] = __builtin_amdgcn_mfma_f32_16x16x32_bf16(pf, vf, o[t], 0, 0, 0);
        }
    }
    float* obase = out + ((size_t)bh * SEQ + q0) * DIM;
#pragma unroll
    for (int t = 0; t < 4; ++t)
#pragma unroll
        for (int r = 0; r < 4; ++r)
            obase[(size_t)(quad * 4 + r) * DIM + t * 16 + n] = o[t][r];
}

// ---------------------------------------------------------------- launch

extern "C" void kernel_launch(void* const* d_in, const int* in_sizes, int n_in,
                              void* d_out, int out_size, void* d_ws, size_t ws_size,
                              hipStream_t stream) {
    const float* q    = (const float*)d_in[0];
    const float* k    = (const float*)d_in[1];
    const float* v    = (const float*)d_in[2];
    const int*   mask = (const int*)d_in[3];

    float* out   = (float*)d_out;
    float* score = out + (size_t)BH * SEQ * DIM;

    const size_t bits_bytes = (size_t)SEQ * SEQ / 8;            // 512 KB
    const size_t kb_bytes   = (size_t)BH * SEQ * DIM * 2;       // 8 MB
    const size_t need_fast  = bits_bytes + 2 * kb_bytes;        // ~16.5 MB

    if (ws_size >= need_fast) {
        unsigned long long* bits = (unsigned long long*)d_ws;
        short* kbuf = (short*)((char*)d_ws + bits_bytes);
        short* vtb  = (short*)((char*)d_ws + bits_bytes + kb_bytes);

        maskbits_kernel<<<(SEQ * SEQ) / 256, 256, 0, stream>>>(mask, bits);
        cvt_k_kernel<<<(BH * SEQ * DIM / 8) / 256, 256, 0, stream>>>(k, kbuf);
        cvt_vt_kernel<<<dim3(SEQ / 64, BH), 256, 0, stream>>>(v, vtb);

        dim3 grid(SEQ / 32, BH);          // 32 q-rows per block, col-split waves
        attn_fast<<<grid, 256, 0, stream>>>(q, kbuf, vtb,
                                            (const unsigned int*)d_ws, out, score);
    } else {
        const int use_bits = (ws_size >= bits_bytes) ? 1 : 0;
        if (use_bits)
            maskbits_kernel<<<(SEQ * SEQ) / 256, 256, 0, stream>>>(
                mask, (unsigned long long*)d_ws);
        dim3 grid(SEQ / 64, BH);
        attn_ref<<<grid, 256, 0, stream>>>(q, k, v, mask,
                                           (const unsigned int*)d_ws, use_bits,
                                           out, score);
    }
}